// Round 1
// baseline (332.130 us; speedup 1.0000x reference)
//
#include <hip/hip_runtime.h>
#include <stdint.h>
#include <stddef.h>

typedef __bf16 bf16;
typedef __attribute__((ext_vector_type(8))) __bf16 bf16x8;
typedef __attribute__((ext_vector_type(4))) __bf16 bf16x4;
typedef __attribute__((ext_vector_type(4))) float f32x4;

// -------- async global->LDS (16B) --------
__device__ __forceinline__ void gload_lds16(const void* g, void* l) {
  __builtin_amdgcn_global_load_lds(
      (const __attribute__((address_space(1))) unsigned int*)g,
      (__attribute__((address_space(3))) unsigned int*)l, 16, 0, 0);
}

// ================= convert x: fp32 -> bf16 =================
__global__ void cvt_bf16_kernel(const float* __restrict__ in, bf16* __restrict__ out, int n) {
  int i = (blockIdx.x * blockDim.x + threadIdx.x) * 4;
  if (i < n) {
    float4 v = *(const float4*)(in + i);
    bf16x4 o;
    o[0] = (bf16)v.x; o[1] = (bf16)v.y; o[2] = (bf16)v.z; o[3] = (bf16)v.w;
    *(bf16x4*)(out + i) = o;
  }
}

// ======= transpose+convert: in[K_][N_] fp32 -> out[N_][K_] bf16 =======
__global__ void transpose_cvt_kernel(const float* __restrict__ in, bf16* __restrict__ out,
                                     int K_, int N_) {
  __shared__ __align__(16) bf16 t[64][65];
  const int nb = blockIdx.x * 64, kb = blockIdx.y * 64;
  const int c = threadIdx.x & 63, r0 = (threadIdx.x >> 6) * 16;
#pragma unroll
  for (int i = 0; i < 16; ++i) {
    int rr = r0 + i;                      // k-local
    t[c][rr] = (bf16)in[(size_t)(kb + rr) * N_ + nb + c];   // coalesced read
  }
  __syncthreads();
#pragma unroll
  for (int i = 0; i < 16; ++i) {
    int rr = r0 + i;                      // n-local
    out[(size_t)(nb + rr) * K_ + kb + c] = t[rr][c];        // coalesced write
  }
}

// ================= GEMM: C[M,N] = A[M,K] * BT[N,K]^T + bias =================
// MODE 0: bf16 output, scale (acc+bias) by qscale for col<qcols (QKV proj)
// MODE 1: fp32 output (final proj)
#define BM 128
#define BN 128
#define BK 64

template <int MODE>
__global__ __launch_bounds__(256) void gemm_bt(
    const bf16* __restrict__ A, const bf16* __restrict__ BT,
    const float* __restrict__ bias, void* __restrict__ Cout,
    int M, int N, int K, float qscale, int qcols) {
  __shared__ __align__(16) bf16 As[BM * BK];
  __shared__ __align__(16) bf16 Bs[BN * BK];
  const int tid = threadIdx.x;
  const int lane = tid & 63;
  const int w = tid >> 6;
  const int wm = (w >> 1) * 64;
  const int wn = (w & 1) * 64;
  const int m0 = blockIdx.x * BM;
  const int n0 = blockIdx.y * BN;
  const int r = lane & 15, g = lane >> 4;

  f32x4 acc[4][4] = {};

  for (int k0 = 0; k0 < K; k0 += BK) {
    __syncthreads();
    // stage A,B tiles: 128x64 bf16 each; XOR-swizzle via pre-swizzled SOURCE chunk
#pragma unroll
    for (int i = 0; i < 4; ++i) {
      int id = tid + i * 256;
      int row = id >> 3, c = id & 7;
      int sc = c ^ (row & 7);
      gload_lds16(A + (size_t)(m0 + row) * K + k0 + sc * 8, As + id * 8);
      gload_lds16(BT + (size_t)(n0 + row) * K + k0 + sc * 8, Bs + id * 8);
    }
    __syncthreads();
#pragma unroll
    for (int s = 0; s < 2; ++s) {
      bf16x8 fa[4], fb[4];
#pragma unroll
      for (int i = 0; i < 4; ++i) {
        int arow = wm + i * 16 + r;
        fa[i] = *(const bf16x8*)(As + arow * 64 + (((s * 4 + g) ^ (arow & 7)) << 3));
        int brow = wn + i * 16 + r;
        fb[i] = *(const bf16x8*)(Bs + brow * 64 + (((s * 4 + g) ^ (brow & 7)) << 3));
      }
#pragma unroll
      for (int i = 0; i < 4; ++i)
#pragma unroll
        for (int j = 0; j < 4; ++j)
          acc[i][j] = __builtin_amdgcn_mfma_f32_16x16x32_bf16(fa[i], fb[j], acc[i][j], 0, 0, 0);
    }
  }

  // epilogue: C/D layout col = lane&15, row = (lane>>4)*4 + reg
#pragma unroll
  for (int i = 0; i < 4; ++i) {
#pragma unroll
    for (int j = 0; j < 4; ++j) {
      int col = n0 + wn + j * 16 + r;
      float b = bias[col];
      float sc = (MODE == 0 && col < qcols) ? qscale : 1.0f;
#pragma unroll
      for (int rr = 0; rr < 4; ++rr) {
        int row = m0 + wm + i * 16 + g * 4 + rr;
        float v = (acc[i][j][rr] + b) * sc;
        if (MODE == 0)
          ((bf16*)Cout)[(size_t)row * N + col] = (bf16)v;
        else
          ((float*)Cout)[(size_t)row * N + col] = v;
      }
    }
  }
}

// ================= fused flash attention =================
// qkv: bf16 [4096][3072], cols = which*1024 + h*64 + d; Q pre-scaled by 0.125*log2e
// out: bf16 [4096][1024], col = h*64 + d
#define QBLK 128
#define KVB 64

__global__ __launch_bounds__(256) void attn_fwd(const bf16* __restrict__ qkv,
                                                bf16* __restrict__ out) {
  const int S = 4096, LD = 3072;
  __shared__ __align__(16) bf16 Kl[KVB * 64];      // [kv][dk], chunk ^= (kv&7)
  __shared__ __align__(16) bf16 Vt[64 * KVB];      // [d][kv],  chunk ^= (d&7)^((d>>3)&7)
  __shared__ __align__(16) bf16 Pl[4][32 * 64];    // per-wave [q][kv], chunk ^= (q&7)^((q>>3)&7)

  const int tid = threadIdx.x, lane = tid & 63, w = tid >> 6;
  const int g = lane >> 4, r = lane & 15;
  const int h = blockIdx.y;
  const int q0 = blockIdx.x * QBLK + w * 32;

  const bf16* Qg = qkv + h * 64;
  const bf16* Kg = qkv + 1024 + h * 64;
  const bf16* Vg = qkv + 2048 + h * 64;

  // Q fragments: aq[qblock][kslice]; A-frag: row = lane&15, k = (lane>>4)*8+j
  bf16x8 aq[2][2];
#pragma unroll
  for (int b = 0; b < 2; ++b)
#pragma unroll
    for (int s = 0; s < 2; ++s)
      aq[b][s] = *(const bf16x8*)(Qg + (size_t)(q0 + b * 16 + r) * LD + s * 32 + g * 8);

  f32x4 o[2][4] = {};
  float m_run[2][4], l_run[2][4];
#pragma unroll
  for (int b = 0; b < 2; ++b)
#pragma unroll
    for (int i = 0; i < 4; ++i) { m_run[b][i] = -1e30f; l_run[b][i] = 0.f; }

  bf16* Pw = Pl[w];

  for (int t0 = 0; t0 < S; t0 += KVB) {
    __syncthreads();  // previous iter's LDS reads done

    // ---- stage K tile via global_load_lds, source-swizzled ----
#pragma unroll
    for (int i = 0; i < 2; ++i) {
      int id = tid + i * 256;
      int row = id >> 3, c = id & 7;
      gload_lds16(Kg + (size_t)(t0 + row) * LD + ((c ^ (row & 7)) * 8), Kl + id * 8);
    }
    // ---- stage V transposed: global -> regs -> swizzled LDS ----
    bf16x8 vreg[2];
#pragma unroll
    for (int i = 0; i < 2; ++i) {
      int id = tid + i * 256;
      int vr = id >> 3, d0 = (id & 7) * 8;
      vreg[i] = *(const bf16x8*)(Vg + (size_t)(t0 + vr) * LD + d0);
    }
#pragma unroll
    for (int i = 0; i < 2; ++i) {
      int id = tid + i * 256;
      int vr = id >> 3, d0c = id & 7;
#pragma unroll
      for (int jj = 0; jj < 8; ++jj) {
        int d = d0c * 8 + jj;
        int key = jj ^ d0c;  // (d&7)^((d>>3)&7)
        Vt[d * 64 + (((vr >> 3) ^ key) << 3) + (vr & 7)] = vreg[i][jj];
      }
    }
    __syncthreads();  // staging complete (drains vmcnt + lgkm)

    // ---- S = Q K^T  (scores already in log2 domain) ----
    f32x4 sf[2][4] = {};
#pragma unroll
    for (int s = 0; s < 2; ++s) {
      bf16x8 kf[4];
#pragma unroll
      for (int jk = 0; jk < 4; ++jk) {
        int krow = jk * 16 + r;
        kf[jk] = *(const bf16x8*)(Kl + krow * 64 + (((s * 4 + g) ^ (krow & 7)) << 3));
      }
#pragma unroll
      for (int b = 0; b < 2; ++b)
#pragma unroll
        for (int jk = 0; jk < 4; ++jk)
          sf[b][jk] = __builtin_amdgcn_mfma_f32_16x16x32_bf16(aq[b][s], kf[jk], sf[b][jk], 0, 0, 0);
    }

    // ---- online softmax; D-layout: row q = b*16 + g*4 + rr, col kv = jk*16 + r ----
#pragma unroll
    for (int b = 0; b < 2; ++b) {
#pragma unroll
      for (int rr = 0; rr < 4; ++rr) {
        float mx = fmaxf(fmaxf(sf[b][0][rr], sf[b][1][rr]), fmaxf(sf[b][2][rr], sf[b][3][rr]));
#pragma unroll
        for (int msk = 1; msk < 16; msk <<= 1) mx = fmaxf(mx, __shfl_xor(mx, msk, 64));
        float mnew = fmaxf(m_run[b][rr], mx);
        float alpha = exp2f(m_run[b][rr] - mnew);
        float psum = 0.f;
#pragma unroll
        for (int jk = 0; jk < 4; ++jk) {
          float p = exp2f(sf[b][jk][rr] - mnew);
          sf[b][jk][rr] = p;
          psum += p;
        }
#pragma unroll
        for (int msk = 1; msk < 16; msk <<= 1) psum += __shfl_xor(psum, msk, 64);
        l_run[b][rr] = l_run[b][rr] * alpha + psum;
        m_run[b][rr] = mnew;
#pragma unroll
        for (int jd = 0; jd < 4; ++jd) o[b][jd][rr] *= alpha;
      }
    }

    // ---- P -> LDS (bf16, swizzled) ----
#pragma unroll
    for (int b = 0; b < 2; ++b)
#pragma unroll
      for (int jk = 0; jk < 4; ++jk)
#pragma unroll
        for (int rr = 0; rr < 4; ++rr) {
          int q = b * 16 + g * 4 + rr;
          int keyq = (q & 7) ^ ((q >> 3) & 7);
          Pw[q * 64 + ((((jk * 2 + (r >> 3)) ^ keyq)) << 3) + (r & 7)] = (bf16)sf[b][jk][rr];
        }
    asm volatile("s_waitcnt lgkmcnt(0)" ::: "memory");
    __builtin_amdgcn_sched_barrier(0);

    // ---- O += P V ----
#pragma unroll
    for (int s = 0; s < 2; ++s) {
      bf16x8 pf[2], vf[4];
#pragma unroll
      for (int b = 0; b < 2; ++b) {
        int q = b * 16 + r;
        int keyq = (q & 7) ^ ((q >> 3) & 7);
        pf[b] = *(const bf16x8*)(Pw + q * 64 + (((s * 4 + g) ^ keyq) << 3));
      }
#pragma unroll
      for (int jd = 0; jd < 4; ++jd) {
        int d = jd * 16 + r;
        int keyd = (d & 7) ^ ((d >> 3) & 7);
        vf[jd] = *(const bf16x8*)(Vt + d * 64 + (((s * 4 + g) ^ keyd) << 3));
      }
#pragma unroll
      for (int b = 0; b < 2; ++b)
#pragma unroll
        for (int jd = 0; jd < 4; ++jd)
          o[b][jd] = __builtin_amdgcn_mfma_f32_16x16x32_bf16(pf[b], vf[jd], o[b][jd], 0, 0, 0);
    }
  }

  // ---- epilogue: normalize and store bf16 ----
#pragma unroll
  for (int b = 0; b < 2; ++b) {
#pragma unroll
    for (int rr = 0; rr < 4; ++rr) {
      float inv = 1.0f / l_run[b][rr];
#pragma unroll
      for (int jd = 0; jd < 4; ++jd) {
        int q = q0 + b * 16 + g * 4 + rr;
        int d = jd * 16 + r;
        out[(size_t)q * 1024 + h * 64 + d] = (bf16)(o[b][jd][rr] * inv);
      }
    }
  }
}

// ================= launcher =================
extern "C" void kernel_launch(void* const* d_in, const int* in_sizes, int n_in,
                              void* d_out, int out_size, void* d_ws, size_t ws_size,
                              hipStream_t stream) {
  const float* x     = (const float*)d_in[0];
  const float* w_qkv = (const float*)d_in[1];
  const float* b_qkv = (const float*)d_in[2];
  const float* w_out = (const float*)d_in[3];
  const float* b_out = (const float*)d_in[4];
  float* outp = (float*)d_out;

  char* ws = (char*)d_ws;
  bf16* qkv   = (bf16*)(ws);                          // [4096][3072]  24 MB
  bf16* xbf   = (bf16*)(ws + 24u * 1024 * 1024);      // [4096][1024]   8 MB (reused as attn_out)
  bf16* wqkvT = (bf16*)(ws + 32u * 1024 * 1024);      // [3072][1024]   6 MB
  bf16* woutT = (bf16*)(ws + 38u * 1024 * 1024);      // [1024][1024]   2 MB

  cvt_bf16_kernel<<<4096, 256, 0, stream>>>(x, xbf, 4096 * 1024);
  transpose_cvt_kernel<<<dim3(48, 16), 256, 0, stream>>>(w_qkv, wqkvT, 1024, 3072);
  transpose_cvt_kernel<<<dim3(16, 16), 256, 0, stream>>>(w_out, woutT, 1024, 1024);

  // QKV projection; fold 1/sqrt(dk) * log2(e) into Q so attention uses exp2 directly
  gemm_bt<0><<<dim3(32, 24), 256, 0, stream>>>(xbf, wqkvT, b_qkv, qkv,
                                               4096, 3072, 1024,
                                               0.125f * 1.44269504088896f, 1024);

  attn_fwd<<<dim3(32, 16), 256, 0, stream>>>(qkv, xbf);  // writes attn_out into xbf

  gemm_bt<1><<<dim3(32, 8), 256, 0, stream>>>(xbf, woutT, b_out, outp,
                                              4096, 1024, 1024, 1.0f, 0);
}

// Round 2
// 237.685 us; speedup vs baseline: 1.3974x; 1.3974x over previous
//
#include <hip/hip_runtime.h>
#include <stdint.h>
#include <stddef.h>

typedef __bf16 bf16;
typedef uint32_t u32;
typedef __attribute__((ext_vector_type(8))) __bf16 bf16x8;
typedef __attribute__((ext_vector_type(4))) __bf16 bf16x4;
typedef __attribute__((ext_vector_type(4))) float f32x4;
typedef __attribute__((ext_vector_type(16))) float f32x16;
typedef __attribute__((ext_vector_type(8))) unsigned short u16x8;
typedef __attribute__((ext_vector_type(4))) u32 u32x4;

// -------- async global->LDS (16B) --------
__device__ __forceinline__ void gload_lds16(const void* g, void* l) {
  __builtin_amdgcn_global_load_lds(
      (const __attribute__((address_space(1))) unsigned int*)g,
      (__attribute__((address_space(3))) unsigned int*)l, 16, 0, 0);
}

__device__ __forceinline__ float fast_exp2(float x) {
#if __has_builtin(__builtin_amdgcn_exp2f)
  return __builtin_amdgcn_exp2f(x);
#else
  float r; asm("v_exp_f32 %0, %1" : "=v"(r) : "v"(x)); return r;
#endif
}

__device__ __forceinline__ u32 cvtpk_bf16(float lo, float hi_) {
  u32 r;
  asm("v_cvt_pk_bf16_f32 %0, %1, %2" : "=v"(r) : "v"(lo), "v"(hi_));
  return r;
}

// swap: a[32:63] <-> b[0:31]  (vdst hi gets vsrc lo; vsrc lo gets old vdst hi)
__device__ __forceinline__ void pl32swap(u32& a, u32& b) {
  asm("v_permlane32_swap_b32 %0, %1" : "+v"(a), "+&v"(b));
}

// ================= convert x: fp32 -> bf16 =================
__global__ void cvt_bf16_kernel(const float* __restrict__ in, bf16* __restrict__ out, int n) {
  int i = (blockIdx.x * blockDim.x + threadIdx.x) * 4;
  if (i < n) {
    float4 v = *(const float4*)(in + i);
    bf16x4 o;
    o[0] = (bf16)v.x; o[1] = (bf16)v.y; o[2] = (bf16)v.z; o[3] = (bf16)v.w;
    *(bf16x4*)(out + i) = o;
  }
}

// ======= transpose+convert: in[K_][N_] fp32 -> out[N_][K_] bf16 =======
__global__ void transpose_cvt_kernel(const float* __restrict__ in, bf16* __restrict__ out,
                                     int K_, int N_) {
  __shared__ __align__(16) bf16 t[64][65];
  const int nb = blockIdx.x * 64, kb = blockIdx.y * 64;
  const int c = threadIdx.x & 63, r0 = (threadIdx.x >> 6) * 16;
#pragma unroll
  for (int i = 0; i < 16; ++i) {
    int rr = r0 + i;
    t[c][rr] = (bf16)in[(size_t)(kb + rr) * N_ + nb + c];
  }
  __syncthreads();
#pragma unroll
  for (int i = 0; i < 16; ++i) {
    int rr = r0 + i;
    out[(size_t)(nb + rr) * K_ + kb + c] = t[rr][c];
  }
}

// ================= GEMM: C[M,N] = A[M,K] * BT[N,K]^T + bias =================
#define BM 128
#define BN 128
#define BK 64

template <int MODE>
__global__ __launch_bounds__(256) void gemm_bt(
    const bf16* __restrict__ A, const bf16* __restrict__ BT,
    const float* __restrict__ bias, void* __restrict__ Cout,
    int M, int N, int K, float qscale, int qcols) {
  __shared__ __align__(16) bf16 As[BM * BK];
  __shared__ __align__(16) bf16 Bs[BN * BK];
  const int tid = threadIdx.x;
  const int lane = tid & 63;
  const int w = tid >> 6;
  const int wm = (w >> 1) * 64;
  const int wn = (w & 1) * 64;
  const int m0 = blockIdx.x * BM;
  const int n0 = blockIdx.y * BN;
  const int r = lane & 15, g = lane >> 4;

  f32x4 acc[4][4] = {};

  for (int k0 = 0; k0 < K; k0 += BK) {
    __syncthreads();
#pragma unroll
    for (int i = 0; i < 4; ++i) {
      int id = tid + i * 256;
      int row = id >> 3, c = id & 7;
      int sc = c ^ (row & 7);
      gload_lds16(A + (size_t)(m0 + row) * K + k0 + sc * 8, As + id * 8);
      gload_lds16(BT + (size_t)(n0 + row) * K + k0 + sc * 8, Bs + id * 8);
    }
    __syncthreads();
#pragma unroll
    for (int s = 0; s < 2; ++s) {
      bf16x8 fa[4], fb[4];
#pragma unroll
      for (int i = 0; i < 4; ++i) {
        int arow = wm + i * 16 + r;
        fa[i] = *(const bf16x8*)(As + arow * 64 + (((s * 4 + g) ^ (arow & 7)) << 3));
        int brow = wn + i * 16 + r;
        fb[i] = *(const bf16x8*)(Bs + brow * 64 + (((s * 4 + g) ^ (brow & 7)) << 3));
      }
#pragma unroll
      for (int i = 0; i < 4; ++i)
#pragma unroll
        for (int j = 0; j < 4; ++j)
          acc[i][j] = __builtin_amdgcn_mfma_f32_16x16x32_bf16(fa[i], fb[j], acc[i][j], 0, 0, 0);
    }
  }

#pragma unroll
  for (int i = 0; i < 4; ++i) {
#pragma unroll
    for (int j = 0; j < 4; ++j) {
      int col = n0 + wn + j * 16 + r;
      float b = bias[col];
      float sc = (MODE == 0 && col < qcols) ? qscale : 1.0f;
#pragma unroll
      for (int rr = 0; rr < 4; ++rr) {
        int row = m0 + wm + i * 16 + g * 4 + rr;
        float v = (acc[i][j][rr] + b) * sc;
        if (MODE == 0)
          ((bf16*)Cout)[(size_t)row * N + col] = (bf16)v;
        else
          ((float*)Cout)[(size_t)row * N + col] = v;
      }
    }
  }
}

// ================= fused flash attention (swapped-operand 32x32) =================
// qkv: bf16 [4096][3072]; Q pre-scaled by 0.125*log2e. out: bf16 [4096][1024].
#define S_LEN 4096
#define LDQ 3072

__global__ __launch_bounds__(256, 2) void attn_fwd2(const bf16* __restrict__ qkv,
                                                    bf16* __restrict__ out) {
  __shared__ __align__(16) bf16 Vt[2][64 * 64];   // [d][kv], chunk ^= (d&7); double-buffered

  const int tid = threadIdx.x, lane = tid & 63, w = tid >> 6;
  const int hi = lane >> 5, q = lane & 31;
  const int h = blockIdx.y;
  const int q0 = blockIdx.x * 128 + w * 32;

  const bf16* Qg = qkv + h * 64;
  const bf16* Kg = qkv + 1024 + h * 64;
  const bf16* Vg = qkv + 2048 + h * 64;

  // Q B-frags: col=q, k = st*16 + hi*8 + j  (row-contiguous in global)
  bf16x8 fq[4];
  {
    const bf16* qp = Qg + (size_t)(q0 + q) * LDQ + hi * 8;
#pragma unroll
    for (int st = 0; st < 4; ++st) fq[st] = *(const bf16x8*)(qp + st * 16);
  }

  f32x16 o0 = {}, o1 = {};
  float m_run = -1e30f, l_run = 0.f;

  // V staging unit: tid -> kv pair, 8-wide d group
  const int kvp = tid & 31, dgrp = tid >> 5;
  const int kv0 = kvp * 2, d0v = dgrp * 8;
  const int kvc = kvp >> 2;      // (2*kvp)>>3
  const int kvw = kv0 & 7;

  bf16x8 kpre[2][8];   // [set][kvh*4+st]
  bf16x8 vpre[2][2];

  auto load_kv = [&](int t0, int set) {
    const bf16* kp0 = Kg + (size_t)(t0 + q) * LDQ + hi * 8;
    const bf16* kp1 = kp0 + (size_t)32 * LDQ;
#pragma unroll
    for (int st = 0; st < 4; ++st) {
      kpre[set][st]     = *(const bf16x8*)(kp0 + st * 16);
      kpre[set][4 + st] = *(const bf16x8*)(kp1 + st * 16);
    }
    const bf16* vp = Vg + (size_t)(t0 + kv0) * LDQ + d0v;
    vpre[set][0] = *(const bf16x8*)(vp);
    vpre[set][1] = *(const bf16x8*)(vp + LDQ);
  };

  auto stage_v = [&](int set, bf16* buf) {
    u16x8 a = __builtin_bit_cast(u16x8, vpre[set][0]);
    u16x8 b = __builtin_bit_cast(u16x8, vpre[set][1]);
#pragma unroll
    for (int j = 0; j < 8; ++j) {
      int d = d0v + j;
      u32 pk = (u32)a[j] | ((u32)b[j] << 16);
      *(u32*)(&buf[d * 64 + ((kvc ^ (d & 7)) << 3) + kvw]) = pk;
    }
  };

  load_kv(0, 0);
  stage_v(0, Vt[0]);
  __syncthreads();

  for (int t = 0; t < 64; t += 2) {
#pragma unroll
    for (int tt = 0; tt < 2; ++tt) {
      const int cur = tt, nxt = tt ^ 1;
      const int t0n = ((t + tt + 1) & 63) * 64;

      // issue next-tile K/V global loads (drain covered by end-of-iter barrier)
      load_kv(t0n, nxt);

      // ---- S^T = K * Q^T : D[kv][q], q = lane&31 ----
      f32x16 p0 = {}, p1 = {};
#pragma unroll
      for (int st = 0; st < 4; ++st) {
        p0 = __builtin_amdgcn_mfma_f32_32x32x16_bf16(kpre[cur][st],     fq[st], p0, 0, 0, 0);
        p1 = __builtin_amdgcn_mfma_f32_32x32x16_bf16(kpre[cur][4 + st], fq[st], p1, 0, 0, 0);
      }

      // ---- in-register softmax for column q ----
      float tm[16];
#pragma unroll
      for (int i = 0; i < 16; ++i) tm[i] = fmaxf(p0[i], p1[i]);
#pragma unroll
      for (int s2 = 8; s2 > 0; s2 >>= 1)
#pragma unroll
        for (int i = 0; i < s2; ++i) tm[i] = fmaxf(tm[i], tm[i + s2]);
      float mx = fmaxf(tm[0], __shfl_xor(tm[0], 32, 64));  // combine with partner half

      if (__any(mx > m_run + 8.0f)) {      // defer-max rescale (wave-uniform)
        float mnew = fmaxf(m_run, mx);
        float alpha = fast_exp2(m_run - mnew);
        l_run *= alpha;
#pragma unroll
        for (int i = 0; i < 16; ++i) { o0[i] *= alpha; o1[i] *= alpha; }
        m_run = mnew;
      }

#pragma unroll
      for (int i = 0; i < 16; ++i) p0[i] = fast_exp2(p0[i] - m_run);
#pragma unroll
      for (int i = 0; i < 16; ++i) p1[i] = fast_exp2(p1[i] - m_run);

      float s8[8];
#pragma unroll
      for (int i = 0; i < 8; ++i) s8[i] = (p0[i] + p0[i + 8]) + (p1[i] + p1[i + 8]);
#pragma unroll
      for (int s2 = 4; s2 > 0; s2 >>= 1)
#pragma unroll
        for (int i = 0; i < s2; ++i) s8[i] += s8[i + s2];
      float ps = s8[0] + __shfl_xor(s8[0], 32, 64);
      l_run += ps;

      // ---- P^T B-frags in-register: 16 cvt_pk + 8 permlane32_swap ----
      u32x4 pb[4];  // pb[ks]: B-frag words for kv block 16*ks
#pragma unroll
      for (int half = 0; half < 2; ++half) {
#pragma unroll
        for (int qd = 0; qd < 2; ++qd) {
          int ks = half * 2 + qd;
          u32 a0, b0, a1, b1;
          if (half == 0) {
            a0 = cvtpk_bf16(p0[qd * 8 + 0], p0[qd * 8 + 1]);
            b0 = cvtpk_bf16(p0[qd * 8 + 4], p0[qd * 8 + 5]);
            a1 = cvtpk_bf16(p0[qd * 8 + 2], p0[qd * 8 + 3]);
            b1 = cvtpk_bf16(p0[qd * 8 + 6], p0[qd * 8 + 7]);
          } else {
            a0 = cvtpk_bf16(p1[qd * 8 + 0], p1[qd * 8 + 1]);
            b0 = cvtpk_bf16(p1[qd * 8 + 4], p1[qd * 8 + 5]);
            a1 = cvtpk_bf16(p1[qd * 8 + 2], p1[qd * 8 + 3]);
            b1 = cvtpk_bf16(p1[qd * 8 + 6], p1[qd * 8 + 7]);
          }
          pl32swap(a0, b0);
          pl32swap(a1, b1);
          pb[ks][0] = a0; pb[ks][1] = a1; pb[ks][2] = b0; pb[ks][3] = b1;
        }
      }

      // ---- O^T += V^T * P^T : D[d][q] ----
      const bf16* vb = Vt[tt];
#pragma unroll
      for (int ks = 0; ks < 4; ++ks) {
        bf16x8 pf = __builtin_bit_cast(bf16x8, pb[ks]);
        int ck = ((2 * ks + hi) ^ (q & 7)) << 3;
        bf16x8 av0 = *(const bf16x8*)(vb + q * 64 + ck);
        bf16x8 av1 = *(const bf16x8*)(vb + (32 + q) * 64 + ck);
        o0 = __builtin_amdgcn_mfma_f32_32x32x16_bf16(av0, pf, o0, 0, 0, 0);
        o1 = __builtin_amdgcn_mfma_f32_32x32x16_bf16(av1, pf, o1, 0, 0, 0);
      }

      // stage next V tile into the other buffer
      stage_v(nxt, Vt[nxt]);
      __syncthreads();
    }
  }

  // ---- epilogue: O^T normalize, pack, store ----
  float inv = 1.0f / l_run;
  bf16* op = out + (size_t)(q0 + q) * 1024 + h * 64;
#pragma unroll
  for (int db = 0; db < 2; ++db) {
#pragma unroll
    for (int rg = 0; rg < 4; ++rg) {
      float e0, e1, e2, e3;
      if (db == 0) {
        e0 = o0[rg * 4 + 0]; e1 = o0[rg * 4 + 1]; e2 = o0[rg * 4 + 2]; e3 = o0[rg * 4 + 3];
      } else {
        e0 = o1[rg * 4 + 0]; e1 = o1[rg * 4 + 1]; e2 = o1[rg * 4 + 2]; e3 = o1[rg * 4 + 3];
      }
      int dbase = db * 32 + rg * 8 + hi * 4;
      uint2 stv;
      stv.x = cvtpk_bf16(e0 * inv, e1 * inv);
      stv.y = cvtpk_bf16(e2 * inv, e3 * inv);
      *(uint2*)(op + dbase) = stv;
    }
  }
}

// ================= launcher =================
extern "C" void kernel_launch(void* const* d_in, const int* in_sizes, int n_in,
                              void* d_out, int out_size, void* d_ws, size_t ws_size,
                              hipStream_t stream) {
  const float* x     = (const float*)d_in[0];
  const float* w_qkv = (const float*)d_in[1];
  const float* b_qkv = (const float*)d_in[2];
  const float* w_out = (const float*)d_in[3];
  const float* b_out = (const float*)d_in[4];
  float* outp = (float*)d_out;

  char* ws = (char*)d_ws;
  bf16* qkv   = (bf16*)(ws);                          // [4096][3072]  24 MB
  bf16* xbf   = (bf16*)(ws + 24u * 1024 * 1024);      // [4096][1024]   8 MB (reused as attn_out)
  bf16* wqkvT = (bf16*)(ws + 32u * 1024 * 1024);      // [3072][1024]   6 MB
  bf16* woutT = (bf16*)(ws + 38u * 1024 * 1024);      // [1024][1024]   2 MB

  cvt_bf16_kernel<<<4096, 256, 0, stream>>>(x, xbf, 4096 * 1024);
  transpose_cvt_kernel<<<dim3(48, 16), 256, 0, stream>>>(w_qkv, wqkvT, 1024, 3072);
  transpose_cvt_kernel<<<dim3(16, 16), 256, 0, stream>>>(w_out, woutT, 1024, 1024);

  gemm_bt<0><<<dim3(32, 24), 256, 0, stream>>>(xbf, wqkvT, b_qkv, qkv,
                                               4096, 3072, 1024,
                                               0.125f * 1.44269504088896f, 1024);

  attn_fwd2<<<dim3(32, 16), 256, 0, stream>>>(qkv, xbf);

  gemm_bt<1><<<dim3(32, 8), 256, 0, stream>>>(xbf, woutT, b_out, outp,
                                              4096, 1024, 1024, 1.0f, 0);
}